// Round 18
// baseline (800.135 us; speedup 1.0000x reference)
//
#include <hip/hip_runtime.h>
#include <hip/hip_bf16.h>
#include <math.h>

#define HF 96

typedef __attribute__((ext_vector_type(8))) short bf16x8;
typedef __attribute__((ext_vector_type(4))) float f32x4;

__device__ __forceinline__ short f2b(float x) {
    __hip_bfloat16 h = __float2bfloat16(x);
    return *reinterpret_cast<short*>(&h);
}
__device__ __forceinline__ float b2f(short s) {
    __hip_bfloat16 h = *reinterpret_cast<__hip_bfloat16*>(&s);
    return __bfloat162float(h);
}

// ---- prep: transpose 5 weight matrices to bf16 [outfeat][k];
//      block 96 (k==HF) additionally computes the bias pack -------------
__global__ void k_prep(const float* __restrict__ Weg, const float* __restrict__ Wsg,
                       const float* __restrict__ Wdg, const float* __restrict__ Wdu,
                       const float* __restrict__ Wsu,
                       const float* __restrict__ timef, const float* __restrict__ Wtp,
                       const float* __restrict__ btp,
                       const float* __restrict__ bsg, const float* __restrict__ bdg,
                       const float* __restrict__ bdu, const float* __restrict__ bsu,
                       short* __restrict__ WegT, short* __restrict__ WT4,
                       float* __restrict__ bias4) {
    int c = threadIdx.x;   // out-feature
    int k = blockIdx.x;    // input k (or HF -> bias block)
    if (c >= HF) return;
    if (k < HF) {
        WegT[c * HF + k]           = f2b(Weg[k * HF + c]);
        WT4[(0 * HF + c) * HF + k] = f2b(Wsg[k * HF + c]);
        WT4[(1 * HF + c) * HF + k] = f2b(Wdg[k * HF + c]);
        WT4[(2 * HF + c) * HF + k] = f2b(Wdu[k * HF + c]);
        WT4[(3 * HF + c) * HF + k] = f2b(Wsu[k * HF + c]);
    } else {
        float acc = btp[c];
#pragma unroll 8
        for (int kk = 0; kk < HF; ++kk) acc = fmaf(timef[kk], Wtp[kk * HF + c], acc);
        bias4[0 * HF + c] = bsg[c] + acc;
        bias4[1 * HF + c] = bdg[c];
        bias4[2 * HF + c] = bdu[c];
        bias4[3 * HF + c] = bsu[c];
    }
}

// ---- CSR build: histogram ----------------------------------------------
__global__ void k_hist(const int* __restrict__ dst, unsigned* __restrict__ counts, int E) {
    int e = blockIdx.x * 256 + threadIdx.x;
    if (e < E) atomicAdd(&counts[dst[e]], 1u);
}

// ---- parallel scan A: per-block (512-chunk) sums, coalesced -------------
__global__ __launch_bounds__(256)
void k_scanA(const unsigned* __restrict__ counts, unsigned* __restrict__ bsum, int n) {
    int b = blockIdx.x, t = threadIdx.x;
    int base = b * 512;
    unsigned s = 0;
    int i0 = base + t, i1 = base + 256 + t;
    if (i0 < n) s += counts[i0];
    if (i1 < n) s += counts[i1];
    __shared__ unsigned ls[256];
    ls[t] = s; __syncthreads();
    for (int off = 128; off > 0; off >>= 1) {
        if (t < off) ls[t] += ls[t + off];
        __syncthreads();
    }
    if (t == 0) bsum[b] = ls[0];
}

// ---- parallel scan C: block offset from bsum + local Hillis-Steele ------
__global__ __launch_bounds__(512)
void k_scanC(const unsigned* __restrict__ counts, const unsigned* __restrict__ bsum,
             unsigned* __restrict__ offs, unsigned* __restrict__ cursor, int n) {
    int b = blockIdx.x, t = threadIdx.x;
    __shared__ unsigned ls[512];
    __shared__ unsigned boffS;

    unsigned s0 = 0;
    for (int i = t; i < b; i += 512) s0 += bsum[i];
    ls[t] = s0; __syncthreads();
    for (int off = 256; off > 0; off >>= 1) {
        if (t < off) ls[t] += ls[t + off];
        __syncthreads();
    }
    if (t == 0) boffS = ls[0];
    __syncthreads();
    unsigned boffv = boffS;
    __syncthreads();

    int i = b * 512 + t;
    unsigned v = (i < n) ? counts[i] : 0u;
    ls[t] = v; __syncthreads();
#pragma unroll
    for (int off = 1; off < 512; off <<= 1) {
        unsigned u = (t >= off) ? ls[t - off] : 0u;
        __syncthreads();
        ls[t] += u;
        __syncthreads();
    }
    unsigned excl = ls[t] - v + boffv;
    if (i < n) { offs[i] = excl; cursor[i] = excl; }
    if (i == n - 1) offs[n] = excl + v;
}

// ---- CSR build: slot_of[e] (coalesced) + srcs_slot[pos] (scattered) -----
__global__ void k_scatter(const int* __restrict__ src, const int* __restrict__ dst,
                          unsigned* __restrict__ cursor,
                          unsigned* __restrict__ slot_of, int* __restrict__ srcs_slot,
                          int E) {
    int e = blockIdx.x * 256 + threadIdx.x;
    if (e < E) {
        int d = dst[e];
        unsigned pos = atomicAdd(&cursor[d], 1u);
        slot_of[e] = pos;
        srcs_slot[pos] = src[e];
    }
}

// load a row's A-fragments (plain bf16) for 3 K-tiles
__device__ __forceinline__ void load_afrag(const float* __restrict__ ap, bf16x8* a) {
#pragma unroll
    for (int kt = 0; kt < 3; ++kt) {
        float4 f0 = *(const float4*)(ap + kt * 32);
        float4 f1 = *(const float4*)(ap + kt * 32 + 4);
        bf16x8 fr;
        fr[0] = f2b(f0.x); fr[1] = f2b(f0.y); fr[2] = f2b(f0.z); fr[3] = f2b(f0.w);
        fr[4] = f2b(f1.x); fr[5] = f2b(f1.y); fr[6] = f2b(f1.z); fr[7] = f2b(f1.w);
        a[kt] = fr;
    }
}

// ---- node GEMMs: esrc16, edstA16, bh16 (all bf16), xlin (f32) -----------
__global__ __launch_bounds__(256)
void k_node_mfma(const float* __restrict__ nf,
                 const short* __restrict__ WT4,
                 const float* __restrict__ bias4,
                 short* __restrict__ esrc16, short* __restrict__ edstA16,
                 short* __restrict__ bh16, float* __restrict__ xlin, int n) {
    int wid = threadIdx.x >> 6;
    int lane = threadIdx.x & 63;
    int lr = lane & 15, lg = lane >> 4;
    int nbase = blockIdx.x * 64 + wid * 16;

    bf16x8 a[3];
    {
        int arow = nbase + lr; if (arow > n - 1) arow = n - 1;
        load_afrag(nf + (size_t)arow * HF + lg * 8, a);
    }

#pragma unroll
    for (int w = 0; w < 4; ++w) {
#pragma unroll
        for (int tn = 0; tn < 6; ++tn) {
            f32x4 acc = {0.f, 0.f, 0.f, 0.f};
            int feat = tn * 16 + lr;
            size_t boff = (size_t)(w * HF + feat) * HF + lg * 8;
#pragma unroll
            for (int kt = 0; kt < 3; ++kt) {
                bf16x8 bfr = *(const bf16x8*)(WT4 + boff + kt * 32);
                acc = __builtin_amdgcn_mfma_f32_16x16x32_bf16(a[kt], bfr, acc, 0, 0, 0);
            }
            float bias = bias4[w * HF + feat];
#pragma unroll
            for (int r = 0; r < 4; ++r) {
                int node = nbase + lg * 4 + r;
                if (node < n) {
                    float v = acc[r] + bias;
                    size_t o = (size_t)node * HF + feat;
                    if (w == 0)      esrc16[o]  = f2b(v);
                    else if (w == 1) edstA16[o] = f2b(v);
                    else if (w == 2) bh16[o]    = f2b(v);
                    else             xlin[o]    = v;
                }
            }
        }
    }
}

// ---- edge (ORIGINAL order): reg-prefetched gathers + gate GEMM + LN -----
__global__ __launch_bounds__(256, 4)
void k_edge_mfma(const float* __restrict__ ef, const int* __restrict__ src,
                 const int* __restrict__ dst, const unsigned* __restrict__ slot_of,
                 const short* __restrict__ WegT,
                 const float* __restrict__ beg,
                 const short* __restrict__ esrc16, const short* __restrict__ edstA16,
                 const float* __restrict__ g_ln, const float* __restrict__ b_ln,
                 unsigned char* __restrict__ sq,
                 float* __restrict__ y, int E) {
    int wid = threadIdx.x >> 6;
    int lane = threadIdx.x & 63;
    int lr = lane & 15, lg = lane >> 4;
    int ebase = blockIdx.x * 64 + wid * 16;

    __shared__ float redS[4][4][64];   // [wid][r][lg*16+lr]
    __shared__ float redQ[4][4][64];

    int e_r[4], s_r[4], d_r[4], sl_r[4];
    bool val[4];
#pragma unroll
    for (int r = 0; r < 4; ++r) {
        e_r[r] = ebase + lg * 4 + r;
        val[r] = (e_r[r] < E);
        int ec = val[r] ? e_r[r] : E - 1;
        s_r[r] = src[ec];
        d_r[r] = dst[ec];
        sl_r[r] = (int)slot_of[ec];
    }

    unsigned short esb[6][4], edb[6][4];
#pragma unroll
    for (int tn = 0; tn < 6; ++tn) {
        int feat = tn * 16 + lr;
#pragma unroll
        for (int r = 0; r < 4; ++r) {
            esb[tn][r] = *(const unsigned short*)&esrc16[(size_t)s_r[r] * HF + feat];
            edb[tn][r] = *(const unsigned short*)&edstA16[(size_t)d_r[r] * HF + feat];
        }
    }

    bf16x8 a[3];
    {
        int arow = ebase + lr; if (arow > E - 1) arow = E - 1;
        load_afrag(ef + (size_t)arow * HF + lg * 8, a);
    }

    f32x4 acc[6];
    __builtin_amdgcn_s_setprio(1);
#pragma unroll
    for (int tn = 0; tn < 6; ++tn) {
        acc[tn] = (f32x4){0.f, 0.f, 0.f, 0.f};
        size_t boff = (size_t)(tn * 16 + lr) * HF + lg * 8;
#pragma unroll
        for (int kt = 0; kt < 3; ++kt) {
            bf16x8 bfr = *(const bf16x8*)(WegT + boff + kt * 32);
            acc[tn] = __builtin_amdgcn_mfma_f32_16x16x32_bf16(a[kt], bfr, acc[tn], 0, 0, 0);
        }
    }
    __builtin_amdgcn_s_setprio(0);

    float psum[4] = {0.f, 0.f, 0.f, 0.f}, psq[4] = {0.f, 0.f, 0.f, 0.f};
#pragma unroll
    for (int tn = 0; tn < 6; ++tn) {
        int feat = tn * 16 + lr;
        float bg = beg[feat];
#pragma unroll
        for (int r = 0; r < 4; ++r) {
            float v = acc[tn][r] + bg
                    + b2f((short)esb[tn][r]) + b2f((short)edb[tn][r]);
            acc[tn][r] = v;
            psum[r] += v;
            psq[r]  += v * v;
            if (val[r]) {
                float sg = 1.0f / (1.0f + __expf(-v));
                int q = __float2int_rn(sg * 255.0f);
                if (q < 1) q = 1;            // avoid zero-weight cliff
                sq[(size_t)sl_r[r] * HF + feat] = (unsigned char)q;
            }
        }
    }

#pragma unroll
    for (int r = 0; r < 4; ++r) {
        redS[wid][r][lg * 16 + lr] = psum[r];
        redQ[wid][r][lg * 16 + lr] = psq[r];
    }
    float mean[4], rstd[4];
#pragma unroll
    for (int r = 0; r < 4; ++r) {
        const float4* ps4 = (const float4*)&redS[wid][r][0];
        const float4* pq4 = (const float4*)&redQ[wid][r][0];
        float s = 0.f, q = 0.f;
#pragma unroll
        for (int i = 0; i < 4; ++i) {
            float4 aa = ps4[lg * 4 + i];
            float4 bb = pq4[lg * 4 + i];
            s += (aa.x + aa.y) + (aa.z + aa.w);
            q += (bb.x + bb.y) + (bb.z + bb.w);
        }
        mean[r] = s * (1.0f / HF);
        float var = q * (1.0f / HF) - mean[r] * mean[r];
        rstd[r] = rsqrtf(var + 1e-5f);
    }

#pragma unroll
    for (int tn = 0; tn < 6; ++tn) {
        int feat = tn * 16 + lr;
        float g = g_ln[feat], bb = b_ln[feat];
#pragma unroll
        for (int r = 0; r < 4; ++r) {
            if (!val[r]) continue;
            float v = acc[tn][r];
            float ln = (v - mean[r]) * rstd[r] * g + bb;
            float si = ln / (1.0f + __expf(-ln));
            size_t oe = (size_t)e_r[r] * HF + feat;
            __builtin_nontemporal_store(ef[oe] + si, &y[oe]);
        }
    }
}

// ---- node finalize: edge-parallel CSR pull (1 node/block, 4 edge lanes),
//      exact integer sums (commutative -> bit-identical), h, LN, SiLU ----
__global__ __launch_bounds__(384)
void k_node_fin(const float* __restrict__ nf,
                const unsigned* __restrict__ offs,
                const int* __restrict__ srcs_slot,
                const unsigned char* __restrict__ sq,
                const short* __restrict__ bh16,
                const float* __restrict__ g_ln, const float* __restrict__ b_ln,
                float* __restrict__ x, int n) {
    int j = threadIdx.x;   // 0..95 feature
    int ty = threadIdx.y;  // 0..3 edge lane
    int node = blockIdx.x;

    unsigned st = offs[node], en = offs[node + 1];
    unsigned den = 0;
    long long num = 0;
    for (unsigned d = st + ty; d < en; d += 4) {
        unsigned q = sq[(size_t)d * HF + j];
        int s = srcs_slot[d];
        int bhi = __float2int_rn(b2f(bh16[(size_t)s * HF + j]) * 4096.0f);
        den += q;
        num += (long long)(int)q * (long long)bhi;
    }

    __shared__ unsigned  denS[4][HF];
    __shared__ long long numS[4][HF];
    __shared__ float reds[HF], redq[HF];
    denS[ty][j] = den;
    numS[ty][j] = num;
    __syncthreads();

    float xv = 0.0f;
    if (ty == 0) {
        unsigned  dt = denS[0][j] + denS[1][j] + denS[2][j] + denS[3][j];
        long long nt = numS[0][j] + numS[1][j] + numS[2][j] + numS[3][j];
        float ssv  = (float)dt * (1.0f / 255.0f);
        float sshv = (float)nt * (1.0f / (255.0f * 4096.0f));
        float h = sshv / (ssv + 1e-6f);
        size_t o = (size_t)node * HF + j;
        xv = x[o] + h;
        reds[j] = xv;
        redq[j] = xv * xv;
    }
    __syncthreads();
    if (ty == 0 && j < 48) { reds[j] += reds[j + 48]; redq[j] += redq[j + 48]; } __syncthreads();
    if (ty == 0 && j < 24) { reds[j] += reds[j + 24]; redq[j] += redq[j + 24]; } __syncthreads();
    if (ty == 0 && j < 12) { reds[j] += reds[j + 12]; redq[j] += redq[j + 12]; } __syncthreads();
    if (ty == 0 && j < 6)  { reds[j] += reds[j + 6];  redq[j] += redq[j + 6];  } __syncthreads();
    if (ty == 0 && j < 3)  { reds[j] += reds[j + 3];  redq[j] += redq[j + 3];  } __syncthreads();

    if (ty == 0) {
        float sum = reds[0] + reds[1] + reds[2];
        float sqv = redq[0] + redq[1] + redq[2];
        float mean = sum * (1.0f / HF);
        float var  = sqv * (1.0f / HF) - mean * mean;
        float lnv  = (xv - mean) * rsqrtf(var + 1e-5f) * g_ln[j] + b_ln[j];
        float silu = lnv / (1.0f + __expf(-lnv));
        size_t o = (size_t)node * HF + j;
        x[o] = nf[o] + silu;
    }
}

extern "C" void kernel_launch(void* const* d_in, const int* in_sizes, int n_in,
                              void* d_out, int out_size, void* d_ws, size_t ws_size,
                              hipStream_t stream) {
    const float* node_feats = (const float*)d_in[0];
    const float* edge_feats = (const float*)d_in[1];
    const float* time_feats = (const float*)d_in[2];
    const int*   src        = (const int*)d_in[3];
    const int*   dst        = (const int*)d_in[4];
    const float* W_tp = (const float*)d_in[5];  const float* b_tp = (const float*)d_in[6];
    const float* W_sg = (const float*)d_in[7];  const float* b_sg = (const float*)d_in[8];
    const float* W_dg = (const float*)d_in[9];  const float* b_dg = (const float*)d_in[10];
    const float* W_eg = (const float*)d_in[11]; const float* b_eg = (const float*)d_in[12];
    const float* W_su = (const float*)d_in[13]; const float* b_su = (const float*)d_in[14];
    const float* W_du = (const float*)d_in[15]; const float* b_du = (const float*)d_in[16];
    const float* g_ln_e = (const float*)d_in[17]; const float* b_ln_e = (const float*)d_in[18];
    const float* g_ln_n = (const float*)d_in[19]; const float* b_ln_n = (const float*)d_in[20];

    int n = in_sizes[0] / HF;   // 100000
    int e = in_sizes[1] / HF;   // 800000

    float* ws    = (float*)d_ws;
    float* bias4 = ws;
    short* WegT  = (short*)(ws + 384);
    short* WT4   = (short*)(ws + 384 + 4608);
    short* esrc16  = (short*)(ws + 384 + 4608 + 18432);
    short* edstA16 = esrc16  + (size_t)n * HF;
    short* bh16    = edstA16 + (size_t)n * HF;
    unsigned char* sq = (unsigned char*)(bh16 + (size_t)n * HF);
    unsigned* slot_of = (unsigned*)(sq + (size_t)e * HF);
    int* srcs_slot    = (int*)(slot_of + (size_t)e);
    unsigned* offs    = (unsigned*)(srcs_slot + (size_t)e);
    unsigned* cursor  = offs + (size_t)(n + 1);
    unsigned* counts  = cursor + (size_t)n;
    unsigned* bsum    = counts + (size_t)n;

    float* x = (float*)d_out;            // [n, H]
    float* y = x + (size_t)n * HF;       // [e, H]

    int nb = (n + 511) / 512;

    hipMemsetAsync(counts, 0, (size_t)n * sizeof(unsigned), stream);

    k_prep<<<HF + 1, HF, 0, stream>>>(W_eg, W_sg, W_dg, W_du, W_su,
                                      time_feats, W_tp, b_tp,
                                      b_sg, b_dg, b_du, b_su,
                                      WegT, WT4, bias4);

    k_hist<<<(e + 255) / 256, 256, 0, stream>>>(dst, counts, e);
    k_scanA<<<nb, 256, 0, stream>>>(counts, bsum, n);
    k_scanC<<<nb, 512, 0, stream>>>(counts, bsum, offs, cursor, n);
    k_scatter<<<(e + 255) / 256, 256, 0, stream>>>(src, dst, cursor, slot_of, srcs_slot, e);

    k_node_mfma<<<(n + 63) / 64, 256, 0, stream>>>(node_feats, WT4, bias4,
                                                   esrc16, edstA16, bh16, x, n);

    k_edge_mfma<<<(e + 63) / 64, 256, 0, stream>>>(edge_feats, src, dst, slot_of,
                                                   WegT, b_eg,
                                                   esrc16, edstA16,
                                                   g_ln_e, b_ln_e,
                                                   sq, y, e);

    dim3 b2(HF, 4);
    k_node_fin<<<n, b2, 0, stream>>>(node_feats, offs, srcs_slot,
                                     sq, bh16,
                                     g_ln_n, b_ln_n, x, n);
}

// Round 19
// 683.444 us; speedup vs baseline: 1.1707x; 1.1707x over previous
//
#include <hip/hip_runtime.h>
#include <hip/hip_bf16.h>
#include <math.h>

#define HF 96

typedef __attribute__((ext_vector_type(8))) short bf16x8;
typedef __attribute__((ext_vector_type(4))) float f32x4;

__device__ __forceinline__ short f2b(float x) {
    __hip_bfloat16 h = __float2bfloat16(x);
    return *reinterpret_cast<short*>(&h);
}
__device__ __forceinline__ float b2f(short s) {
    __hip_bfloat16 h = *reinterpret_cast<__hip_bfloat16*>(&s);
    return __bfloat162float(h);
}

// ---- prep: transpose 5 weight matrices to bf16 [outfeat][k];
//      block 96 (k==HF) additionally computes the bias pack -------------
__global__ void k_prep(const float* __restrict__ Weg, const float* __restrict__ Wsg,
                       const float* __restrict__ Wdg, const float* __restrict__ Wdu,
                       const float* __restrict__ Wsu,
                       const float* __restrict__ timef, const float* __restrict__ Wtp,
                       const float* __restrict__ btp,
                       const float* __restrict__ bsg, const float* __restrict__ bdg,
                       const float* __restrict__ bdu, const float* __restrict__ bsu,
                       short* __restrict__ WegT, short* __restrict__ WT4,
                       float* __restrict__ bias4) {
    int c = threadIdx.x;   // out-feature
    int k = blockIdx.x;    // input k (or HF -> bias block)
    if (c >= HF) return;
    if (k < HF) {
        WegT[c * HF + k]           = f2b(Weg[k * HF + c]);
        WT4[(0 * HF + c) * HF + k] = f2b(Wsg[k * HF + c]);
        WT4[(1 * HF + c) * HF + k] = f2b(Wdg[k * HF + c]);
        WT4[(2 * HF + c) * HF + k] = f2b(Wdu[k * HF + c]);
        WT4[(3 * HF + c) * HF + k] = f2b(Wsu[k * HF + c]);
    } else {
        float acc = btp[c];
#pragma unroll 8
        for (int kk = 0; kk < HF; ++kk) acc = fmaf(timef[kk], Wtp[kk * HF + c], acc);
        bias4[0 * HF + c] = bsg[c] + acc;
        bias4[1 * HF + c] = bdg[c];
        bias4[2 * HF + c] = bdu[c];
        bias4[3 * HF + c] = bsu[c];
    }
}

// ---- CSR build: histogram ----------------------------------------------
__global__ void k_hist(const int* __restrict__ dst, unsigned* __restrict__ counts, int E) {
    int e = blockIdx.x * 256 + threadIdx.x;
    if (e < E) atomicAdd(&counts[dst[e]], 1u);
}

// ---- parallel scan A: per-block (512-chunk) sums, coalesced -------------
__global__ __launch_bounds__(256)
void k_scanA(const unsigned* __restrict__ counts, unsigned* __restrict__ bsum, int n) {
    int b = blockIdx.x, t = threadIdx.x;
    int base = b * 512;
    unsigned s = 0;
    int i0 = base + t, i1 = base + 256 + t;
    if (i0 < n) s += counts[i0];
    if (i1 < n) s += counts[i1];
    __shared__ unsigned ls[256];
    ls[t] = s; __syncthreads();
    for (int off = 128; off > 0; off >>= 1) {
        if (t < off) ls[t] += ls[t + off];
        __syncthreads();
    }
    if (t == 0) bsum[b] = ls[0];
}

// ---- parallel scan C: block offset from bsum + local Hillis-Steele ------
__global__ __launch_bounds__(512)
void k_scanC(const unsigned* __restrict__ counts, const unsigned* __restrict__ bsum,
             unsigned* __restrict__ offs, unsigned* __restrict__ cursor, int n) {
    int b = blockIdx.x, t = threadIdx.x;
    __shared__ unsigned ls[512];
    __shared__ unsigned boffS;

    unsigned s0 = 0;
    for (int i = t; i < b; i += 512) s0 += bsum[i];
    ls[t] = s0; __syncthreads();
    for (int off = 256; off > 0; off >>= 1) {
        if (t < off) ls[t] += ls[t + off];
        __syncthreads();
    }
    if (t == 0) boffS = ls[0];
    __syncthreads();
    unsigned boffv = boffS;
    __syncthreads();

    int i = b * 512 + t;
    unsigned v = (i < n) ? counts[i] : 0u;
    ls[t] = v; __syncthreads();
#pragma unroll
    for (int off = 1; off < 512; off <<= 1) {
        unsigned u = (t >= off) ? ls[t - off] : 0u;
        __syncthreads();
        ls[t] += u;
        __syncthreads();
    }
    unsigned excl = ls[t] - v + boffv;
    if (i < n) { offs[i] = excl; cursor[i] = excl; }
    if (i == n - 1) offs[n] = excl + v;
}

// ---- CSR build: slot_of[e] (coalesced) + srcs_slot[pos] (scattered) -----
__global__ void k_scatter(const int* __restrict__ src, const int* __restrict__ dst,
                          unsigned* __restrict__ cursor,
                          unsigned* __restrict__ slot_of, int* __restrict__ srcs_slot,
                          int E) {
    int e = blockIdx.x * 256 + threadIdx.x;
    if (e < E) {
        int d = dst[e];
        unsigned pos = atomicAdd(&cursor[d], 1u);
        slot_of[e] = pos;
        srcs_slot[pos] = src[e];
    }
}

// load a row's A-fragments (plain bf16) for 3 K-tiles
__device__ __forceinline__ void load_afrag(const float* __restrict__ ap, bf16x8* a) {
#pragma unroll
    for (int kt = 0; kt < 3; ++kt) {
        float4 f0 = *(const float4*)(ap + kt * 32);
        float4 f1 = *(const float4*)(ap + kt * 32 + 4);
        bf16x8 fr;
        fr[0] = f2b(f0.x); fr[1] = f2b(f0.y); fr[2] = f2b(f0.z); fr[3] = f2b(f0.w);
        fr[4] = f2b(f1.x); fr[5] = f2b(f1.y); fr[6] = f2b(f1.z); fr[7] = f2b(f1.w);
        a[kt] = fr;
    }
}

// ---- node GEMMs: esrc16, edstA16, bh16 (all bf16), xlin (f32) -----------
__global__ __launch_bounds__(256)
void k_node_mfma(const float* __restrict__ nf,
                 const short* __restrict__ WT4,
                 const float* __restrict__ bias4,
                 short* __restrict__ esrc16, short* __restrict__ edstA16,
                 short* __restrict__ bh16, float* __restrict__ xlin, int n) {
    int wid = threadIdx.x >> 6;
    int lane = threadIdx.x & 63;
    int lr = lane & 15, lg = lane >> 4;
    int nbase = blockIdx.x * 64 + wid * 16;

    bf16x8 a[3];
    {
        int arow = nbase + lr; if (arow > n - 1) arow = n - 1;
        load_afrag(nf + (size_t)arow * HF + lg * 8, a);
    }

#pragma unroll
    for (int w = 0; w < 4; ++w) {
#pragma unroll
        for (int tn = 0; tn < 6; ++tn) {
            f32x4 acc = {0.f, 0.f, 0.f, 0.f};
            int feat = tn * 16 + lr;
            size_t boff = (size_t)(w * HF + feat) * HF + lg * 8;
#pragma unroll
            for (int kt = 0; kt < 3; ++kt) {
                bf16x8 bfr = *(const bf16x8*)(WT4 + boff + kt * 32);
                acc = __builtin_amdgcn_mfma_f32_16x16x32_bf16(a[kt], bfr, acc, 0, 0, 0);
            }
            float bias = bias4[w * HF + feat];
#pragma unroll
            for (int r = 0; r < 4; ++r) {
                int node = nbase + lg * 4 + r;
                if (node < n) {
                    float v = acc[r] + bias;
                    size_t o = (size_t)node * HF + feat;
                    if (w == 0)      esrc16[o]  = f2b(v);
                    else if (w == 1) edstA16[o] = f2b(v);
                    else if (w == 2) bh16[o]    = f2b(v);
                    else             xlin[o]    = v;
                }
            }
        }
    }
}

// ---- edge (ORIGINAL order): reg-prefetched gathers + gate GEMM + LN -----
// (256,4): <=128 unified regs -> 4 waves/SIMD spill-free; setprio around
// the MFMA cluster (barrier-free waves = T5's favorable regime).
__global__ __launch_bounds__(256, 4)
void k_edge_mfma(const float* __restrict__ ef, const int* __restrict__ src,
                 const int* __restrict__ dst, const unsigned* __restrict__ slot_of,
                 const short* __restrict__ WegT,
                 const float* __restrict__ beg,
                 const short* __restrict__ esrc16, const short* __restrict__ edstA16,
                 const float* __restrict__ g_ln, const float* __restrict__ b_ln,
                 unsigned char* __restrict__ sq,
                 float* __restrict__ y, int E) {
    int wid = threadIdx.x >> 6;
    int lane = threadIdx.x & 63;
    int lr = lane & 15, lg = lane >> 4;
    int ebase = blockIdx.x * 64 + wid * 16;

    __shared__ float redS[4][4][64];   // [wid][r][lg*16+lr]
    __shared__ float redQ[4][4][64];

    // 1) edge meta first (enables early gather issue)
    int e_r[4], s_r[4], d_r[4], sl_r[4];
    bool val[4];
#pragma unroll
    for (int r = 0; r < 4; ++r) {
        e_r[r] = ebase + lg * 4 + r;
        val[r] = (e_r[r] < E);
        int ec = val[r] ? e_r[r] : E - 1;
        s_r[r] = src[ec];
        d_r[r] = dst[ec];
        sl_r[r] = (int)slot_of[ec];
    }

    // 2) issue ALL 48 gathers into registers (static arrays, unrolled)
    unsigned short esb[6][4], edb[6][4];
#pragma unroll
    for (int tn = 0; tn < 6; ++tn) {
        int feat = tn * 16 + lr;
#pragma unroll
        for (int r = 0; r < 4; ++r) {
            esb[tn][r] = *(const unsigned short*)&esrc16[(size_t)s_r[r] * HF + feat];
            edb[tn][r] = *(const unsigned short*)&edstA16[(size_t)d_r[r] * HF + feat];
        }
    }

    // 3) A fragments from ef
    bf16x8 a[3];
    {
        int arow = ebase + lr; if (arow > E - 1) arow = E - 1;
        load_afrag(ef + (size_t)arow * HF + lg * 8, a);
    }

    // 4) gate GEMM (hides gather latency); setprio keeps matrix pipe fed
    f32x4 acc[6];
    __builtin_amdgcn_s_setprio(1);
#pragma unroll
    for (int tn = 0; tn < 6; ++tn) {
        acc[tn] = (f32x4){0.f, 0.f, 0.f, 0.f};
        size_t boff = (size_t)(tn * 16 + lr) * HF + lg * 8;
#pragma unroll
        for (int kt = 0; kt < 3; ++kt) {
            bf16x8 bfr = *(const bf16x8*)(WegT + boff + kt * 32);
            acc[tn] = __builtin_amdgcn_mfma_f32_16x16x32_bf16(a[kt], bfr, acc[tn], 0, 0, 0);
        }
    }
    __builtin_amdgcn_s_setprio(0);

    // 5) combine: m = acc + beg + esrc + edst; sigma(u8)->slot; LN partials
    float psum[4] = {0.f, 0.f, 0.f, 0.f}, psq[4] = {0.f, 0.f, 0.f, 0.f};
#pragma unroll
    for (int tn = 0; tn < 6; ++tn) {
        int feat = tn * 16 + lr;
        float bg = beg[feat];
#pragma unroll
        for (int r = 0; r < 4; ++r) {
            float v = acc[tn][r] + bg
                    + b2f((short)esb[tn][r]) + b2f((short)edb[tn][r]);
            acc[tn][r] = v;
            psum[r] += v;
            psq[r]  += v * v;
            if (val[r]) {
                float sg = 1.0f / (1.0f + __expf(-v));
                int q = __float2int_rn(sg * 255.0f);
                if (q < 1) q = 1;            // avoid zero-weight cliff
                sq[(size_t)sl_r[r] * HF + feat] = (unsigned char)q;
            }
        }
    }

    // in-wave LDS reduction of LN partials
#pragma unroll
    for (int r = 0; r < 4; ++r) {
        redS[wid][r][lg * 16 + lr] = psum[r];
        redQ[wid][r][lg * 16 + lr] = psq[r];
    }
    float mean[4], rstd[4];
#pragma unroll
    for (int r = 0; r < 4; ++r) {
        const float4* ps4 = (const float4*)&redS[wid][r][0];
        const float4* pq4 = (const float4*)&redQ[wid][r][0];
        float s = 0.f, q = 0.f;
#pragma unroll
        for (int i = 0; i < 4; ++i) {
            float4 aa = ps4[lg * 4 + i];
            float4 bb = pq4[lg * 4 + i];
            s += (aa.x + aa.y) + (aa.z + aa.w);
            q += (bb.x + bb.y) + (bb.z + bb.w);
        }
        mean[r] = s * (1.0f / HF);
        float var = q * (1.0f / HF) - mean[r] * mean[r];
        rstd[r] = rsqrtf(var + 1e-5f);
    }

    // LN + SiLU + residual, coalesced y write at original edge id
#pragma unroll
    for (int tn = 0; tn < 6; ++tn) {
        int feat = tn * 16 + lr;
        float g = g_ln[feat], bb = b_ln[feat];
#pragma unroll
        for (int r = 0; r < 4; ++r) {
            if (!val[r]) continue;
            float v = acc[tn][r];
            float ln = (v - mean[r]) * rstd[r] * g + bb;
            float si = ln / (1.0f + __expf(-ln));
            size_t oe = (size_t)e_r[r] * HF + feat;
            __builtin_nontemporal_store(ef[oe] + si, &y[oe]);
        }
    }
}

// ---- node finalize: chunked-prefetch CSR pull, h, LN, SiLU, residual ----
__global__ void k_node_fin(const float* __restrict__ nf,
                           const unsigned* __restrict__ offs,
                           const int* __restrict__ srcs_slot,
                           const unsigned char* __restrict__ sq,
                           const short* __restrict__ bh16,
                           const float* __restrict__ g_ln, const float* __restrict__ b_ln,
                           float* __restrict__ x, int n) {
    int j = threadIdx.x;
    int ty = threadIdx.y;
    int node = blockIdx.x * 4 + ty;
    bool valid = (node < n);

    float xv = 0.0f;
    if (valid) {
        unsigned st = offs[node], en = offs[node + 1];
        unsigned den = 0;
        long long num = 0;
        unsigned d = st;
        while (d < en) {
            unsigned cnt = en - d; if (cnt > 8u) cnt = 8u;
            int sarr[8]; unsigned qarr[8];
#pragma unroll
            for (int i = 0; i < 8; ++i) {
                if ((unsigned)i < cnt) {
                    sarr[i] = srcs_slot[d + i];
                    qarr[i] = sq[(size_t)(d + i) * HF + j];
                }
            }
            int barr[8];
#pragma unroll
            for (int i = 0; i < 8; ++i) {
                if ((unsigned)i < cnt)
                    barr[i] = __float2int_rn(b2f(bh16[(size_t)sarr[i] * HF + j]) * 4096.0f);
            }
#pragma unroll
            for (int i = 0; i < 8; ++i) {
                if ((unsigned)i < cnt) {
                    den += qarr[i];
                    num += (long long)(int)qarr[i] * (long long)barr[i];
                }
            }
            d += cnt;
        }
        float ssv  = (float)den * (1.0f / 255.0f);
        float sshv = (float)num * (1.0f / (255.0f * 4096.0f));
        float h = sshv / (ssv + 1e-6f);
        size_t o = (size_t)node * HF + j;
        xv = x[o] + h;
    }

    __shared__ float reds[4][HF];
    __shared__ float redq[4][HF];
    reds[ty][j] = xv;
    redq[ty][j] = xv * xv;
    __syncthreads();
    if (j < 48) { reds[ty][j] += reds[ty][j + 48]; redq[ty][j] += redq[ty][j + 48]; } __syncthreads();
    if (j < 24) { reds[ty][j] += reds[ty][j + 24]; redq[ty][j] += redq[ty][j + 24]; } __syncthreads();
    if (j < 12) { reds[ty][j] += reds[ty][j + 12]; redq[ty][j] += redq[ty][j + 12]; } __syncthreads();
    if (j < 6)  { reds[ty][j] += reds[ty][j + 6];  redq[ty][j] += redq[ty][j + 6];  } __syncthreads();
    if (j < 3)  { reds[ty][j] += reds[ty][j + 3];  redq[ty][j] += redq[ty][j + 3];  } __syncthreads();

    if (valid) {
        float sum = reds[ty][0] + reds[ty][1] + reds[ty][2];
        float sqv = redq[ty][0] + redq[ty][1] + redq[ty][2];
        float mean = sum * (1.0f / HF);
        float var  = sqv * (1.0f / HF) - mean * mean;
        float lnv  = (xv - mean) * rsqrtf(var + 1e-5f) * g_ln[j] + b_ln[j];
        float silu = lnv / (1.0f + __expf(-lnv));
        size_t o = (size_t)node * HF + j;
        x[o] = nf[o] + silu;
    }
}

extern "C" void kernel_launch(void* const* d_in, const int* in_sizes, int n_in,
                              void* d_out, int out_size, void* d_ws, size_t ws_size,
                              hipStream_t stream) {
    const float* node_feats = (const float*)d_in[0];
    const float* edge_feats = (const float*)d_in[1];
    const float* time_feats = (const float*)d_in[2];
    const int*   src        = (const int*)d_in[3];
    const int*   dst        = (const int*)d_in[4];
    const float* W_tp = (const float*)d_in[5];  const float* b_tp = (const float*)d_in[6];
    const float* W_sg = (const float*)d_in[7];  const float* b_sg = (const float*)d_in[8];
    const float* W_dg = (const float*)d_in[9];  const float* b_dg = (const float*)d_in[10];
    const float* W_eg = (const float*)d_in[11]; const float* b_eg = (const float*)d_in[12];
    const float* W_su = (const float*)d_in[13]; const float* b_su = (const float*)d_in[14];
    const float* W_du = (const float*)d_in[15]; const float* b_du = (const float*)d_in[16];
    const float* g_ln_e = (const float*)d_in[17]; const float* b_ln_e = (const float*)d_in[18];
    const float* g_ln_n = (const float*)d_in[19]; const float* b_ln_n = (const float*)d_in[20];

    int n = in_sizes[0] / HF;   // 100000
    int e = in_sizes[1] / HF;   // 800000

    float* ws    = (float*)d_ws;
    float* bias4 = ws;
    short* WegT  = (short*)(ws + 384);
    short* WT4   = (short*)(ws + 384 + 4608);
    short* esrc16  = (short*)(ws + 384 + 4608 + 18432);
    short* edstA16 = esrc16  + (size_t)n * HF;
    short* bh16    = edstA16 + (size_t)n * HF;
    unsigned char* sq = (unsigned char*)(bh16 + (size_t)n * HF);
    unsigned* slot_of = (unsigned*)(sq + (size_t)e * HF);
    int* srcs_slot    = (int*)(slot_of + (size_t)e);
    unsigned* offs    = (unsigned*)(srcs_slot + (size_t)e);
    unsigned* cursor  = offs + (size_t)(n + 1);
    unsigned* counts  = cursor + (size_t)n;
    unsigned* bsum    = counts + (size_t)n;

    float* x = (float*)d_out;            // [n, H]
    float* y = x + (size_t)n * HF;       // [e, H]

    int nb = (n + 511) / 512;

    hipMemsetAsync(counts, 0, (size_t)n * sizeof(unsigned), stream);

    k_prep<<<HF + 1, HF, 0, stream>>>(W_eg, W_sg, W_dg, W_du, W_su,
                                      time_feats, W_tp, b_tp,
                                      b_sg, b_dg, b_du, b_su,
                                      WegT, WT4, bias4);

    k_hist<<<(e + 255) / 256, 256, 0, stream>>>(dst, counts, e);
    k_scanA<<<nb, 256, 0, stream>>>(counts, bsum, n);
    k_scanC<<<nb, 512, 0, stream>>>(counts, bsum, offs, cursor, n);
    k_scatter<<<(e + 255) / 256, 256, 0, stream>>>(src, dst, cursor, slot_of, srcs_slot, e);

    k_node_mfma<<<(n + 63) / 64, 256, 0, stream>>>(node_feats, WT4, bias4,
                                                   esrc16, edstA16, bh16, x, n);

    k_edge_mfma<<<(e + 63) / 64, 256, 0, stream>>>(edge_feats, src, dst, slot_of,
                                                   WegT, b_eg,
                                                   esrc16, edstA16,
                                                   g_ln_e, b_ln_e,
                                                   sq, y, e);

    dim3 b2(HF, 4);
    k_node_fin<<<(n + 3) / 4, b2, 0, stream>>>(node_feats, offs, srcs_slot,
                                               sq, bh16,
                                               g_ln_n, b_ln_n, x, n);
}

// Round 20
// 671.044 us; speedup vs baseline: 1.1924x; 1.0185x over previous
//
#include <hip/hip_runtime.h>
#include <hip/hip_bf16.h>
#include <math.h>

#define HF 96

typedef __attribute__((ext_vector_type(8))) short bf16x8;
typedef __attribute__((ext_vector_type(4))) float f32x4;

__device__ __forceinline__ short f2b(float x) {
    __hip_bfloat16 h = __float2bfloat16(x);
    return *reinterpret_cast<short*>(&h);
}
__device__ __forceinline__ float b2f(short s) {
    __hip_bfloat16 h = *reinterpret_cast<__hip_bfloat16*>(&s);
    return __bfloat162float(h);
}

// ---- prep: transpose 5 weight matrices to bf16 [outfeat][k];
//      block 96 (k==HF) additionally computes the bias pack -------------
__global__ void k_prep(const float* __restrict__ Weg, const float* __restrict__ Wsg,
                       const float* __restrict__ Wdg, const float* __restrict__ Wdu,
                       const float* __restrict__ Wsu,
                       const float* __restrict__ timef, const float* __restrict__ Wtp,
                       const float* __restrict__ btp,
                       const float* __restrict__ bsg, const float* __restrict__ bdg,
                       const float* __restrict__ bdu, const float* __restrict__ bsu,
                       short* __restrict__ WegT, short* __restrict__ WT4,
                       float* __restrict__ bias4) {
    int c = threadIdx.x;   // out-feature
    int k = blockIdx.x;    // input k (or HF -> bias block)
    if (c >= HF) return;
    if (k < HF) {
        WegT[c * HF + k]           = f2b(Weg[k * HF + c]);
        WT4[(0 * HF + c) * HF + k] = f2b(Wsg[k * HF + c]);
        WT4[(1 * HF + c) * HF + k] = f2b(Wdg[k * HF + c]);
        WT4[(2 * HF + c) * HF + k] = f2b(Wdu[k * HF + c]);
        WT4[(3 * HF + c) * HF + k] = f2b(Wsu[k * HF + c]);
    } else {
        float acc = btp[c];
#pragma unroll 8
        for (int kk = 0; kk < HF; ++kk) acc = fmaf(timef[kk], Wtp[kk * HF + c], acc);
        bias4[0 * HF + c] = bsg[c] + acc;
        bias4[1 * HF + c] = bdg[c];
        bias4[2 * HF + c] = bdu[c];
        bias4[3 * HF + c] = bsu[c];
    }
}

// ---- CSR build: histogram ----------------------------------------------
__global__ void k_hist(const int* __restrict__ dst, unsigned* __restrict__ counts, int E) {
    int e = blockIdx.x * 256 + threadIdx.x;
    if (e < E) atomicAdd(&counts[dst[e]], 1u);
}

// ---- parallel scan A: per-block (512-chunk) sums, coalesced -------------
__global__ __launch_bounds__(256)
void k_scanA(const unsigned* __restrict__ counts, unsigned* __restrict__ bsum, int n) {
    int b = blockIdx.x, t = threadIdx.x;
    int base = b * 512;
    unsigned s = 0;
    int i0 = base + t, i1 = base + 256 + t;
    if (i0 < n) s += counts[i0];
    if (i1 < n) s += counts[i1];
    __shared__ unsigned ls[256];
    ls[t] = s; __syncthreads();
    for (int off = 128; off > 0; off >>= 1) {
        if (t < off) ls[t] += ls[t + off];
        __syncthreads();
    }
    if (t == 0) bsum[b] = ls[0];
}

// ---- parallel scan C: block offset from bsum + local Hillis-Steele ------
__global__ __launch_bounds__(512)
void k_scanC(const unsigned* __restrict__ counts, const unsigned* __restrict__ bsum,
             unsigned* __restrict__ offs, unsigned* __restrict__ cursor, int n) {
    int b = blockIdx.x, t = threadIdx.x;
    __shared__ unsigned ls[512];
    __shared__ unsigned boffS;

    unsigned s0 = 0;
    for (int i = t; i < b; i += 512) s0 += bsum[i];
    ls[t] = s0; __syncthreads();
    for (int off = 256; off > 0; off >>= 1) {
        if (t < off) ls[t] += ls[t + off];
        __syncthreads();
    }
    if (t == 0) boffS = ls[0];
    __syncthreads();
    unsigned boffv = boffS;
    __syncthreads();

    int i = b * 512 + t;
    unsigned v = (i < n) ? counts[i] : 0u;
    ls[t] = v; __syncthreads();
#pragma unroll
    for (int off = 1; off < 512; off <<= 1) {
        unsigned u = (t >= off) ? ls[t - off] : 0u;
        __syncthreads();
        ls[t] += u;
        __syncthreads();
    }
    unsigned excl = ls[t] - v + boffv;
    if (i < n) { offs[i] = excl; cursor[i] = excl; }
    if (i == n - 1) offs[n] = excl + v;
}

// load a row's A-fragments (plain bf16) for 3 K-tiles
__device__ __forceinline__ void load_afrag(const float* __restrict__ ap, bf16x8* a) {
#pragma unroll
    for (int kt = 0; kt < 3; ++kt) {
        float4 f0 = *(const float4*)(ap + kt * 32);
        float4 f1 = *(const float4*)(ap + kt * 32 + 4);
        bf16x8 fr;
        fr[0] = f2b(f0.x); fr[1] = f2b(f0.y); fr[2] = f2b(f0.z); fr[3] = f2b(f0.w);
        fr[4] = f2b(f1.x); fr[5] = f2b(f1.y); fr[6] = f2b(f1.z); fr[7] = f2b(f1.w);
        a[kt] = fr;
    }
}

// ---- node GEMMs: esrc16, edstA16, bh16 (all bf16), xlin (f32) -----------
__global__ __launch_bounds__(256)
void k_node_mfma(const float* __restrict__ nf,
                 const short* __restrict__ WT4,
                 const float* __restrict__ bias4,
                 short* __restrict__ esrc16, short* __restrict__ edstA16,
                 short* __restrict__ bh16, float* __restrict__ xlin, int n) {
    int wid = threadIdx.x >> 6;
    int lane = threadIdx.x & 63;
    int lr = lane & 15, lg = lane >> 4;
    int nbase = blockIdx.x * 64 + wid * 16;

    bf16x8 a[3];
    {
        int arow = nbase + lr; if (arow > n - 1) arow = n - 1;
        load_afrag(nf + (size_t)arow * HF + lg * 8, a);
    }

#pragma unroll
    for (int w = 0; w < 4; ++w) {
#pragma unroll
        for (int tn = 0; tn < 6; ++tn) {
            f32x4 acc = {0.f, 0.f, 0.f, 0.f};
            int feat = tn * 16 + lr;
            size_t boff = (size_t)(w * HF + feat) * HF + lg * 8;
#pragma unroll
            for (int kt = 0; kt < 3; ++kt) {
                bf16x8 bfr = *(const bf16x8*)(WT4 + boff + kt * 32);
                acc = __builtin_amdgcn_mfma_f32_16x16x32_bf16(a[kt], bfr, acc, 0, 0, 0);
            }
            float bias = bias4[w * HF + feat];
#pragma unroll
            for (int r = 0; r < 4; ++r) {
                int node = nbase + lg * 4 + r;
                if (node < n) {
                    float v = acc[r] + bias;
                    size_t o = (size_t)node * HF + feat;
                    if (w == 0)      esrc16[o]  = f2b(v);
                    else if (w == 1) edstA16[o] = f2b(v);
                    else if (w == 2) bh16[o]    = f2b(v);
                    else             xlin[o]    = v;
                }
            }
        }
    }
}

// ---- edge (ORIGINAL order): inline CSR slot-claim + reg-prefetched
//      gathers + gate GEMM + sq->slot + fused LN/SiLU/residual -----------
// (256,4): <=128 unified regs -> 4 waves/SIMD spill-free; setprio around
// the MFMA cluster (barrier-free waves = T5's favorable regime).
__global__ __launch_bounds__(256, 4)
void k_edge_mfma(const float* __restrict__ ef, const int* __restrict__ src,
                 const int* __restrict__ dst,
                 unsigned* __restrict__ cursor, int* __restrict__ srcs_slot,
                 const short* __restrict__ WegT,
                 const float* __restrict__ beg,
                 const short* __restrict__ esrc16, const short* __restrict__ edstA16,
                 const float* __restrict__ g_ln, const float* __restrict__ b_ln,
                 unsigned char* __restrict__ sq,
                 float* __restrict__ y, int E) {
    int wid = threadIdx.x >> 6;
    int lane = threadIdx.x & 63;
    int lr = lane & 15, lg = lane >> 4;
    int ebase = blockIdx.x * 64 + wid * 16;

    __shared__ float redS[4][4][64];   // [wid][r][lg*16+lr]
    __shared__ float redQ[4][4][64];
    __shared__ int   slS[4][16];       // [wid][lg*4+r] claimed CSR slots

    // 1) edge meta first (enables early gather issue)
    int e_r[4], s_r[4], d_r[4], sl_r[4];
    bool val[4];
#pragma unroll
    for (int r = 0; r < 4; ++r) {
        e_r[r] = ebase + lg * 4 + r;
        val[r] = (e_r[r] < E);
        int ec = val[r] ? e_r[r] : E - 1;
        s_r[r] = src[ec];
        d_r[r] = dst[ec];
    }

    // 1b) merged k_scatter: one lane per edge claims the CSR slot and
    //     writes srcs_slot; broadcast through in-wave LDS (no barrier:
    //     same wave writes then reads, LDS ops are in-order per wave).
    if (lr == 0) {
#pragma unroll
        for (int r = 0; r < 4; ++r) {
            unsigned pos = 0u;
            if (val[r]) {
                pos = atomicAdd(&cursor[d_r[r]], 1u);
                srcs_slot[pos] = s_r[r];
            }
            slS[wid][lg * 4 + r] = (int)pos;
        }
    }
#pragma unroll
    for (int r = 0; r < 4; ++r) sl_r[r] = slS[wid][lg * 4 + r];

    // 2) issue ALL 48 gathers into registers (static arrays, unrolled)
    unsigned short esb[6][4], edb[6][4];
#pragma unroll
    for (int tn = 0; tn < 6; ++tn) {
        int feat = tn * 16 + lr;
#pragma unroll
        for (int r = 0; r < 4; ++r) {
            esb[tn][r] = *(const unsigned short*)&esrc16[(size_t)s_r[r] * HF + feat];
            edb[tn][r] = *(const unsigned short*)&edstA16[(size_t)d_r[r] * HF + feat];
        }
    }

    // 3) A fragments from ef
    bf16x8 a[3];
    {
        int arow = ebase + lr; if (arow > E - 1) arow = E - 1;
        load_afrag(ef + (size_t)arow * HF + lg * 8, a);
    }

    // 4) gate GEMM (hides gather+atomic latency); setprio keeps pipe fed
    f32x4 acc[6];
    __builtin_amdgcn_s_setprio(1);
#pragma unroll
    for (int tn = 0; tn < 6; ++tn) {
        acc[tn] = (f32x4){0.f, 0.f, 0.f, 0.f};
        size_t boff = (size_t)(tn * 16 + lr) * HF + lg * 8;
#pragma unroll
        for (int kt = 0; kt < 3; ++kt) {
            bf16x8 bfr = *(const bf16x8*)(WegT + boff + kt * 32);
            acc[tn] = __builtin_amdgcn_mfma_f32_16x16x32_bf16(a[kt], bfr, acc[tn], 0, 0, 0);
        }
    }
    __builtin_amdgcn_s_setprio(0);

    // 5) combine: m = acc + beg + esrc + edst; sigma(u8)->slot; LN partials
    float psum[4] = {0.f, 0.f, 0.f, 0.f}, psq[4] = {0.f, 0.f, 0.f, 0.f};
#pragma unroll
    for (int tn = 0; tn < 6; ++tn) {
        int feat = tn * 16 + lr;
        float bg = beg[feat];
#pragma unroll
        for (int r = 0; r < 4; ++r) {
            float v = acc[tn][r] + bg
                    + b2f((short)esb[tn][r]) + b2f((short)edb[tn][r]);
            acc[tn][r] = v;
            psum[r] += v;
            psq[r]  += v * v;
            if (val[r]) {
                float sg = 1.0f / (1.0f + __expf(-v));
                int q = __float2int_rn(sg * 255.0f);
                if (q < 1) q = 1;            // avoid zero-weight cliff
                sq[(size_t)sl_r[r] * HF + feat] = (unsigned char)q;
            }
        }
    }

    // in-wave LDS reduction of LN partials
#pragma unroll
    for (int r = 0; r < 4; ++r) {
        redS[wid][r][lg * 16 + lr] = psum[r];
        redQ[wid][r][lg * 16 + lr] = psq[r];
    }
    float mean[4], rstd[4];
#pragma unroll
    for (int r = 0; r < 4; ++r) {
        const float4* ps4 = (const float4*)&redS[wid][r][0];
        const float4* pq4 = (const float4*)&redQ[wid][r][0];
        float s = 0.f, q = 0.f;
#pragma unroll
        for (int i = 0; i < 4; ++i) {
            float4 aa = ps4[lg * 4 + i];
            float4 bb = pq4[lg * 4 + i];
            s += (aa.x + aa.y) + (aa.z + aa.w);
            q += (bb.x + bb.y) + (bb.z + bb.w);
        }
        mean[r] = s * (1.0f / HF);
        float var = q * (1.0f / HF) - mean[r] * mean[r];
        rstd[r] = rsqrtf(var + 1e-5f);
    }

    // LN + SiLU + residual, coalesced y write at original edge id
#pragma unroll
    for (int tn = 0; tn < 6; ++tn) {
        int feat = tn * 16 + lr;
        float g = g_ln[feat], bb = b_ln[feat];
#pragma unroll
        for (int r = 0; r < 4; ++r) {
            if (!val[r]) continue;
            float v = acc[tn][r];
            float ln = (v - mean[r]) * rstd[r] * g + bb;
            float si = ln / (1.0f + __expf(-ln));
            size_t oe = (size_t)e_r[r] * HF + feat;
            __builtin_nontemporal_store(ef[oe] + si, &y[oe]);
        }
    }
}

// ---- node finalize: chunked-prefetch CSR pull, h, LN, SiLU, residual ----
__global__ void k_node_fin(const float* __restrict__ nf,
                           const unsigned* __restrict__ offs,
                           const int* __restrict__ srcs_slot,
                           const unsigned char* __restrict__ sq,
                           const short* __restrict__ bh16,
                           const float* __restrict__ g_ln, const float* __restrict__ b_ln,
                           float* __restrict__ x, int n) {
    int j = threadIdx.x;
    int ty = threadIdx.y;
    int node = blockIdx.x * 4 + ty;
    bool valid = (node < n);

    float xv = 0.0f;
    if (valid) {
        unsigned st = offs[node], en = offs[node + 1];
        unsigned den = 0;
        long long num = 0;
        unsigned d = st;
        while (d < en) {
            unsigned cnt = en - d; if (cnt > 8u) cnt = 8u;
            int sarr[8]; unsigned qarr[8];
#pragma unroll
            for (int i = 0; i < 8; ++i) {
                if ((unsigned)i < cnt) {
                    sarr[i] = srcs_slot[d + i];
                    qarr[i] = sq[(size_t)(d + i) * HF + j];
                }
            }
            int barr[8];
#pragma unroll
            for (int i = 0; i < 8; ++i) {
                if ((unsigned)i < cnt)
                    barr[i] = __float2int_rn(b2f(bh16[(size_t)sarr[i] * HF + j]) * 4096.0f);
            }
#pragma unroll
            for (int i = 0; i < 8; ++i) {
                if ((unsigned)i < cnt) {
                    den += qarr[i];
                    num += (long long)(int)qarr[i] * (long long)barr[i];
                }
            }
            d += cnt;
        }
        float ssv  = (float)den * (1.0f / 255.0f);
        float sshv = (float)num * (1.0f / (255.0f * 4096.0f));
        float h = sshv / (ssv + 1e-6f);
        size_t o = (size_t)node * HF + j;
        xv = x[o] + h;
    }

    __shared__ float reds[4][HF];
    __shared__ float redq[4][HF];
    reds[ty][j] = xv;
    redq[ty][j] = xv * xv;
    __syncthreads();
    if (j < 48) { reds[ty][j] += reds[ty][j + 48]; redq[ty][j] += redq[ty][j + 48]; } __syncthreads();
    if (j < 24) { reds[ty][j] += reds[ty][j + 24]; redq[ty][j] += redq[ty][j + 24]; } __syncthreads();
    if (j < 12) { reds[ty][j] += reds[ty][j + 12]; redq[ty][j] += redq[ty][j + 12]; } __syncthreads();
    if (j < 6)  { reds[ty][j] += reds[ty][j + 6];  redq[ty][j] += redq[ty][j + 6];  } __syncthreads();
    if (j < 3)  { reds[ty][j] += reds[ty][j + 3];  redq[ty][j] += redq[ty][j + 3];  } __syncthreads();

    if (valid) {
        float sum = reds[ty][0] + reds[ty][1] + reds[ty][2];
        float sqv = redq[ty][0] + redq[ty][1] + redq[ty][2];
        float mean = sum * (1.0f / HF);
        float var  = sqv * (1.0f / HF) - mean * mean;
        float lnv  = (xv - mean) * rsqrtf(var + 1e-5f) * g_ln[j] + b_ln[j];
        float silu = lnv / (1.0f + __expf(-lnv));
        size_t o = (size_t)node * HF + j;
        x[o] = nf[o] + silu;
    }
}

extern "C" void kernel_launch(void* const* d_in, const int* in_sizes, int n_in,
                              void* d_out, int out_size, void* d_ws, size_t ws_size,
                              hipStream_t stream) {
    const float* node_feats = (const float*)d_in[0];
    const float* edge_feats = (const float*)d_in[1];
    const float* time_feats = (const float*)d_in[2];
    const int*   src        = (const int*)d_in[3];
    const int*   dst        = (const int*)d_in[4];
    const float* W_tp = (const float*)d_in[5];  const float* b_tp = (const float*)d_in[6];
    const float* W_sg = (const float*)d_in[7];  const float* b_sg = (const float*)d_in[8];
    const float* W_dg = (const float*)d_in[9];  const float* b_dg = (const float*)d_in[10];
    const float* W_eg = (const float*)d_in[11]; const float* b_eg = (const float*)d_in[12];
    const float* W_su = (const float*)d_in[13]; const float* b_su = (const float*)d_in[14];
    const float* W_du = (const float*)d_in[15]; const float* b_du = (const float*)d_in[16];
    const float* g_ln_e = (const float*)d_in[17]; const float* b_ln_e = (const float*)d_in[18];
    const float* g_ln_n = (const float*)d_in[19]; const float* b_ln_n = (const float*)d_in[20];

    int n = in_sizes[0] / HF;   // 100000
    int e = in_sizes[1] / HF;   // 800000

    // ws layout (float units):
    // bias4[384] | WegT(4608) | WT4(18432)
    // | esrc16 n*96 sh | edstA16 n*96 sh | bh16 n*96 sh | sq E*96 u8
    // | srcs_slot E i32 | offs n+1 | cursor n | counts n | bsum nb
    float* ws    = (float*)d_ws;
    float* bias4 = ws;
    short* WegT  = (short*)(ws + 384);
    short* WT4   = (short*)(ws + 384 + 4608);
    short* esrc16  = (short*)(ws + 384 + 4608 + 18432);
    short* edstA16 = esrc16  + (size_t)n * HF;
    short* bh16    = edstA16 + (size_t)n * HF;
    unsigned char* sq = (unsigned char*)(bh16 + (size_t)n * HF);
    int* srcs_slot    = (int*)(sq + (size_t)e * HF);
    unsigned* offs    = (unsigned*)(srcs_slot + (size_t)e);
    unsigned* cursor  = offs + (size_t)(n + 1);
    unsigned* counts  = cursor + (size_t)n;
    unsigned* bsum    = counts + (size_t)n;

    float* x = (float*)d_out;            // [n, H]
    float* y = x + (size_t)n * HF;       // [e, H]

    int nb = (n + 511) / 512;

    hipMemsetAsync(counts, 0, (size_t)n * sizeof(unsigned), stream);

    k_prep<<<HF + 1, HF, 0, stream>>>(W_eg, W_sg, W_dg, W_du, W_su,
                                      time_feats, W_tp, b_tp,
                                      b_sg, b_dg, b_du, b_su,
                                      WegT, WT4, bias4);

    k_hist<<<(e + 255) / 256, 256, 0, stream>>>(dst, counts, e);
    k_scanA<<<nb, 256, 0, stream>>>(counts, bsum, n);
    k_scanC<<<nb, 512, 0, stream>>>(counts, bsum, offs, cursor, n);

    k_node_mfma<<<(n + 63) / 64, 256, 0, stream>>>(node_feats, WT4, bias4,
                                                   esrc16, edstA16, bh16, x, n);

    k_edge_mfma<<<(e + 63) / 64, 256, 0, stream>>>(edge_feats, src, dst,
                                                   cursor, srcs_slot,
                                                   WegT, b_eg,
                                                   esrc16, edstA16,
                                                   g_ln_e, b_ln_e,
                                                   sq, y, e);

    dim3 b2(HF, 4);
    k_node_fin<<<(n + 3) / 4, b2, 0, stream>>>(node_feats, offs, srcs_slot,
                                               sq, bh16,
                                               g_ln_n, b_ln_n, x, n);
}

// Round 21
// 654.281 us; speedup vs baseline: 1.2229x; 1.0256x over previous
//
#include <hip/hip_runtime.h>
#include <hip/hip_bf16.h>
#include <math.h>

#define HF 96

typedef __attribute__((ext_vector_type(8))) short bf16x8;
typedef __attribute__((ext_vector_type(4))) float f32x4;

__device__ __forceinline__ short f2b(float x) {
    __hip_bfloat16 h = __float2bfloat16(x);
    return *reinterpret_cast<short*>(&h);
}
__device__ __forceinline__ float b2f(short s) {
    __hip_bfloat16 h = *reinterpret_cast<__hip_bfloat16*>(&s);
    return __bfloat162float(h);
}

// ---- prep: transpose 5 weight matrices to bf16 [outfeat][k];
//      block 96 (k==HF) additionally computes the bias pack -------------
__global__ void k_prep(const float* __restrict__ Weg, const float* __restrict__ Wsg,
                       const float* __restrict__ Wdg, const float* __restrict__ Wdu,
                       const float* __restrict__ Wsu,
                       const float* __restrict__ timef, const float* __restrict__ Wtp,
                       const float* __restrict__ btp,
                       const float* __restrict__ bsg, const float* __restrict__ bdg,
                       const float* __restrict__ bdu, const float* __restrict__ bsu,
                       short* __restrict__ WegT, short* __restrict__ WT4,
                       float* __restrict__ bias4) {
    int c = threadIdx.x;   // out-feature
    int k = blockIdx.x;    // input k (or HF -> bias block)
    if (c >= HF) return;
    if (k < HF) {
        WegT[c * HF + k]           = f2b(Weg[k * HF + c]);
        WT4[(0 * HF + c) * HF + k] = f2b(Wsg[k * HF + c]);
        WT4[(1 * HF + c) * HF + k] = f2b(Wdg[k * HF + c]);
        WT4[(2 * HF + c) * HF + k] = f2b(Wdu[k * HF + c]);
        WT4[(3 * HF + c) * HF + k] = f2b(Wsu[k * HF + c]);
    } else {
        float acc = btp[c];
#pragma unroll 8
        for (int kk = 0; kk < HF; ++kk) acc = fmaf(timef[kk], Wtp[kk * HF + c], acc);
        bias4[0 * HF + c] = bsg[c] + acc;
        bias4[1 * HF + c] = bdg[c];
        bias4[2 * HF + c] = bdu[c];
        bias4[3 * HF + c] = bsu[c];
    }
}

// ---- CSR build: histogram ----------------------------------------------
__global__ void k_hist(const int* __restrict__ dst, unsigned* __restrict__ counts, int E) {
    int e = blockIdx.x * 256 + threadIdx.x;
    if (e < E) atomicAdd(&counts[dst[e]], 1u);
}

// ---- parallel scan A: per-block (512-chunk) sums, coalesced -------------
__global__ __launch_bounds__(256)
void k_scanA(const unsigned* __restrict__ counts, unsigned* __restrict__ bsum, int n) {
    int b = blockIdx.x, t = threadIdx.x;
    int base = b * 512;
    unsigned s = 0;
    int i0 = base + t, i1 = base + 256 + t;
    if (i0 < n) s += counts[i0];
    if (i1 < n) s += counts[i1];
    __shared__ unsigned ls[256];
    ls[t] = s; __syncthreads();
    for (int off = 128; off > 0; off >>= 1) {
        if (t < off) ls[t] += ls[t + off];
        __syncthreads();
    }
    if (t == 0) bsum[b] = ls[0];
}

// ---- parallel scan C: block offset from bsum + local Hillis-Steele ------
__global__ __launch_bounds__(512)
void k_scanC(const unsigned* __restrict__ counts, const unsigned* __restrict__ bsum,
             unsigned* __restrict__ offs, unsigned* __restrict__ cursor, int n) {
    int b = blockIdx.x, t = threadIdx.x;
    __shared__ unsigned ls[512];
    __shared__ unsigned boffS;

    unsigned s0 = 0;
    for (int i = t; i < b; i += 512) s0 += bsum[i];
    ls[t] = s0; __syncthreads();
    for (int off = 256; off > 0; off >>= 1) {
        if (t < off) ls[t] += ls[t + off];
        __syncthreads();
    }
    if (t == 0) boffS = ls[0];
    __syncthreads();
    unsigned boffv = boffS;
    __syncthreads();

    int i = b * 512 + t;
    unsigned v = (i < n) ? counts[i] : 0u;
    ls[t] = v; __syncthreads();
#pragma unroll
    for (int off = 1; off < 512; off <<= 1) {
        unsigned u = (t >= off) ? ls[t - off] : 0u;
        __syncthreads();
        ls[t] += u;
        __syncthreads();
    }
    unsigned excl = ls[t] - v + boffv;
    if (i < n) { offs[i] = excl; cursor[i] = excl; }
    if (i == n - 1) offs[n] = excl + v;
}

// load a row's A-fragments (plain bf16) for 3 K-tiles
__device__ __forceinline__ void load_afrag(const float* __restrict__ ap, bf16x8* a) {
#pragma unroll
    for (int kt = 0; kt < 3; ++kt) {
        float4 f0 = *(const float4*)(ap + kt * 32);
        float4 f1 = *(const float4*)(ap + kt * 32 + 4);
        bf16x8 fr;
        fr[0] = f2b(f0.x); fr[1] = f2b(f0.y); fr[2] = f2b(f0.z); fr[3] = f2b(f0.w);
        fr[4] = f2b(f1.x); fr[5] = f2b(f1.y); fr[6] = f2b(f1.z); fr[7] = f2b(f1.w);
        a[kt] = fr;
    }
}

// ---- node GEMMs: esrc16, edstA16, bh16 (all bf16), xlin (f32) -----------
__global__ __launch_bounds__(256)
void k_node_mfma(const float* __restrict__ nf,
                 const short* __restrict__ WT4,
                 const float* __restrict__ bias4,
                 short* __restrict__ esrc16, short* __restrict__ edstA16,
                 short* __restrict__ bh16, float* __restrict__ xlin, int n) {
    int wid = threadIdx.x >> 6;
    int lane = threadIdx.x & 63;
    int lr = lane & 15, lg = lane >> 4;
    int nbase = blockIdx.x * 64 + wid * 16;

    bf16x8 a[3];
    {
        int arow = nbase + lr; if (arow > n - 1) arow = n - 1;
        load_afrag(nf + (size_t)arow * HF + lg * 8, a);
    }

#pragma unroll
    for (int w = 0; w < 4; ++w) {
#pragma unroll
        for (int tn = 0; tn < 6; ++tn) {
            f32x4 acc = {0.f, 0.f, 0.f, 0.f};
            int feat = tn * 16 + lr;
            size_t boff = (size_t)(w * HF + feat) * HF + lg * 8;
#pragma unroll
            for (int kt = 0; kt < 3; ++kt) {
                bf16x8 bfr = *(const bf16x8*)(WT4 + boff + kt * 32);
                acc = __builtin_amdgcn_mfma_f32_16x16x32_bf16(a[kt], bfr, acc, 0, 0, 0);
            }
            float bias = bias4[w * HF + feat];
#pragma unroll
            for (int r = 0; r < 4; ++r) {
                int node = nbase + lg * 4 + r;
                if (node < n) {
                    float v = acc[r] + bias;
                    size_t o = (size_t)node * HF + feat;
                    if (w == 0)      esrc16[o]  = f2b(v);
                    else if (w == 1) edstA16[o] = f2b(v);
                    else if (w == 2) bh16[o]    = f2b(v);
                    else             xlin[o]    = v;
                }
            }
        }
    }
}

// ---- edge (ORIGINAL order): parallel inline CSR slot-claim +
//      reg-prefetched gathers + gate GEMM + sq->slot + fused LN ----------
__global__ __launch_bounds__(256, 4)
void k_edge_mfma(const float* __restrict__ ef, const int* __restrict__ src,
                 const int* __restrict__ dst,
                 unsigned* __restrict__ cursor, int* __restrict__ srcs_slot,
                 const short* __restrict__ WegT,
                 const float* __restrict__ beg,
                 const short* __restrict__ esrc16, const short* __restrict__ edstA16,
                 const float* __restrict__ g_ln, const float* __restrict__ b_ln,
                 unsigned char* __restrict__ sq,
                 float* __restrict__ y, int E) {
    int wid = threadIdx.x >> 6;
    int lane = threadIdx.x & 63;
    int lr = lane & 15, lg = lane >> 4;
    int ebase = blockIdx.x * 64 + wid * 16;

    __shared__ float redS[4][4][64];   // [wid][r][lg*16+lr]
    __shared__ float redQ[4][4][64];
    __shared__ int   slS[4][16];       // [wid][lg*4+r] claimed CSR slots

    // 1) edge meta first (enables early gather issue)
    int e_r[4], s_r[4], d_r[4], sl_r[4];
    bool val[4];
#pragma unroll
    for (int r = 0; r < 4; ++r) {
        e_r[r] = ebase + lg * 4 + r;
        val[r] = (e_r[r] < E);
        int ec = val[r] ? e_r[r] : E - 1;
        s_r[r] = src[ec];
        d_r[r] = dst[ec];
    }

    // 1b) merged k_scatter, PARALLEL claim: lanes with lr<4 each claim one
    //     edge (lg, r=lr) -> 16 atomics issue in ONE wave instruction.
    //     Broadcast via in-wave LDS (same-wave write->read, in-order).
    if (lr < 4) {
        int r = lr;
        unsigned pos = 0u;
        if (val[r]) {
            pos = atomicAdd(&cursor[d_r[r]], 1u);
            srcs_slot[pos] = s_r[r];
        }
        slS[wid][lg * 4 + r] = (int)pos;
    }
#pragma unroll
    for (int r = 0; r < 4; ++r) sl_r[r] = slS[wid][lg * 4 + r];

    // 2) issue ALL 48 gathers into registers (static arrays, unrolled)
    unsigned short esb[6][4], edb[6][4];
#pragma unroll
    for (int tn = 0; tn < 6; ++tn) {
        int feat = tn * 16 + lr;
#pragma unroll
        for (int r = 0; r < 4; ++r) {
            esb[tn][r] = *(const unsigned short*)&esrc16[(size_t)s_r[r] * HF + feat];
            edb[tn][r] = *(const unsigned short*)&edstA16[(size_t)d_r[r] * HF + feat];
        }
    }

    // 3) A fragments from ef
    bf16x8 a[3];
    {
        int arow = ebase + lr; if (arow > E - 1) arow = E - 1;
        load_afrag(ef + (size_t)arow * HF + lg * 8, a);
    }

    // 4) gate GEMM (hides gather+atomic latency); setprio keeps pipe fed
    f32x4 acc[6];
    __builtin_amdgcn_s_setprio(1);
#pragma unroll
    for (int tn = 0; tn < 6; ++tn) {
        acc[tn] = (f32x4){0.f, 0.f, 0.f, 0.f};
        size_t boff = (size_t)(tn * 16 + lr) * HF + lg * 8;
#pragma unroll
        for (int kt = 0; kt < 3; ++kt) {
            bf16x8 bfr = *(const bf16x8*)(WegT + boff + kt * 32);
            acc[tn] = __builtin_amdgcn_mfma_f32_16x16x32_bf16(a[kt], bfr, acc[tn], 0, 0, 0);
        }
    }
    __builtin_amdgcn_s_setprio(0);

    // 5) combine: m = acc + beg + esrc + edst; sigma(u8)->slot; LN partials
    float psum[4] = {0.f, 0.f, 0.f, 0.f}, psq[4] = {0.f, 0.f, 0.f, 0.f};
#pragma unroll
    for (int tn = 0; tn < 6; ++tn) {
        int feat = tn * 16 + lr;
        float bg = beg[feat];
#pragma unroll
        for (int r = 0; r < 4; ++r) {
            float v = acc[tn][r] + bg
                    + b2f((short)esb[tn][r]) + b2f((short)edb[tn][r]);
            acc[tn][r] = v;
            psum[r] += v;
            psq[r]  += v * v;
            if (val[r]) {
                float sg = 1.0f / (1.0f + __expf(-v));
                int q = __float2int_rn(sg * 255.0f);
                if (q < 1) q = 1;            // avoid zero-weight cliff
                sq[(size_t)sl_r[r] * HF + feat] = (unsigned char)q;
            }
        }
    }

    // in-wave LDS reduction of LN partials
#pragma unroll
    for (int r = 0; r < 4; ++r) {
        redS[wid][r][lg * 16 + lr] = psum[r];
        redQ[wid][r][lg * 16 + lr] = psq[r];
    }
    float mean[4], rstd[4];
#pragma unroll
    for (int r = 0; r < 4; ++r) {
        const float4* ps4 = (const float4*)&redS[wid][r][0];
        const float4* pq4 = (const float4*)&redQ[wid][r][0];
        float s = 0.f, q = 0.f;
#pragma unroll
        for (int i = 0; i < 4; ++i) {
            float4 aa = ps4[lg * 4 + i];
            float4 bb = pq4[lg * 4 + i];
            s += (aa.x + aa.y) + (aa.z + aa.w);
            q += (bb.x + bb.y) + (bb.z + bb.w);
        }
        mean[r] = s * (1.0f / HF);
        float var = q * (1.0f / HF) - mean[r] * mean[r];
        rstd[r] = rsqrtf(var + 1e-5f);
    }

    // LN + SiLU + residual, coalesced y write at original edge id
#pragma unroll
    for (int tn = 0; tn < 6; ++tn) {
        int feat = tn * 16 + lr;
        float g = g_ln[feat], bb = b_ln[feat];
#pragma unroll
        for (int r = 0; r < 4; ++r) {
            if (!val[r]) continue;
            float v = acc[tn][r];
            float ln = (v - mean[r]) * rstd[r] * g + bb;
            float si = ln / (1.0f + __expf(-ln));
            size_t oe = (size_t)e_r[r] * HF + feat;
            __builtin_nontemporal_store(ef[oe] + si, &y[oe]);
        }
    }
}

// ---- node finalize: chunked-prefetch CSR pull, h, LN, SiLU, residual ----
__global__ void k_node_fin(const float* __restrict__ nf,
                           const unsigned* __restrict__ offs,
                           const int* __restrict__ srcs_slot,
                           const unsigned char* __restrict__ sq,
                           const short* __restrict__ bh16,
                           const float* __restrict__ g_ln, const float* __restrict__ b_ln,
                           float* __restrict__ x, int n) {
    int j = threadIdx.x;
    int ty = threadIdx.y;
    int node = blockIdx.x * 4 + ty;
    bool valid = (node < n);

    float xv = 0.0f;
    if (valid) {
        unsigned st = offs[node], en = offs[node + 1];
        unsigned den = 0;
        long long num = 0;
        unsigned d = st;
        while (d < en) {
            unsigned cnt = en - d; if (cnt > 8u) cnt = 8u;
            int sarr[8]; unsigned qarr[8];
#pragma unroll
            for (int i = 0; i < 8; ++i) {
                if ((unsigned)i < cnt) {
                    sarr[i] = srcs_slot[d + i];
                    qarr[i] = sq[(size_t)(d + i) * HF + j];
                }
            }
            int barr[8];
#pragma unroll
            for (int i = 0; i < 8; ++i) {
                if ((unsigned)i < cnt)
                    barr[i] = __float2int_rn(b2f(bh16[(size_t)sarr[i] * HF + j]) * 4096.0f);
            }
#pragma unroll
            for (int i = 0; i < 8; ++i) {
                if ((unsigned)i < cnt) {
                    den += qarr[i];
                    num += (long long)(int)qarr[i] * (long long)barr[i];
                }
            }
            d += cnt;
        }
        float ssv  = (float)den * (1.0f / 255.0f);
        float sshv = (float)num * (1.0f / (255.0f * 4096.0f));
        float h = sshv / (ssv + 1e-6f);
        size_t o = (size_t)node * HF + j;
        xv = x[o] + h;
    }

    __shared__ float reds[4][HF];
    __shared__ float redq[4][HF];
    reds[ty][j] = xv;
    redq[ty][j] = xv * xv;
    __syncthreads();
    if (j < 48) { reds[ty][j] += reds[ty][j + 48]; redq[ty][j] += redq[ty][j + 48]; } __syncthreads();
    if (j < 24) { reds[ty][j] += reds[ty][j + 24]; redq[ty][j] += redq[ty][j + 24]; } __syncthreads();
    if (j < 12) { reds[ty][j] += reds[ty][j + 12]; redq[ty][j] += redq[ty][j + 12]; } __syncthreads();
    if (j < 6)  { reds[ty][j] += reds[ty][j + 6];  redq[ty][j] += redq[ty][j + 6];  } __syncthreads();
    if (j < 3)  { reds[ty][j] += reds[ty][j + 3];  redq[ty][j] += redq[ty][j + 3];  } __syncthreads();

    if (valid) {
        float sum = reds[ty][0] + reds[ty][1] + reds[ty][2];
        float sqv = redq[ty][0] + redq[ty][1] + redq[ty][2];
        float mean = sum * (1.0f / HF);
        float var  = sqv * (1.0f / HF) - mean * mean;
        float lnv  = (xv - mean) * rsqrtf(var + 1e-5f) * g_ln[j] + b_ln[j];
        float silu = lnv / (1.0f + __expf(-lnv));
        size_t o = (size_t)node * HF + j;
        x[o] = nf[o] + silu;
    }
}

extern "C" void kernel_launch(void* const* d_in, const int* in_sizes, int n_in,
                              void* d_out, int out_size, void* d_ws, size_t ws_size,
                              hipStream_t stream) {
    const float* node_feats = (const float*)d_in[0];
    const float* edge_feats = (const float*)d_in[1];
    const float* time_feats = (const float*)d_in[2];
    const int*   src        = (const int*)d_in[3];
    const int*   dst        = (const int*)d_in[4];
    const float* W_tp = (const float*)d_in[5];  const float* b_tp = (const float*)d_in[6];
    const float* W_sg = (const float*)d_in[7];  const float* b_sg = (const float*)d_in[8];
    const float* W_dg = (const float*)d_in[9];  const float* b_dg = (const float*)d_in[10];
    const float* W_eg = (const float*)d_in[11]; const float* b_eg = (const float*)d_in[12];
    const float* W_su = (const float*)d_in[13]; const float* b_su = (const float*)d_in[14];
    const float* W_du = (const float*)d_in[15]; const float* b_du = (const float*)d_in[16];
    const float* g_ln_e = (const float*)d_in[17]; const float* b_ln_e = (const float*)d_in[18];
    const float* g_ln_n = (const float*)d_in[19]; const float* b_ln_n = (const float*)d_in[20];

    int n = in_sizes[0] / HF;   // 100000
    int e = in_sizes[1] / HF;   // 800000

    float* ws    = (float*)d_ws;
    float* bias4 = ws;
    short* WegT  = (short*)(ws + 384);
    short* WT4   = (short*)(ws + 384 + 4608);
    short* esrc16  = (short*)(ws + 384 + 4608 + 18432);
    short* edstA16 = esrc16  + (size_t)n * HF;
    short* bh16    = edstA16 + (size_t)n * HF;
    unsigned char* sq = (unsigned char*)(bh16 + (size_t)n * HF);
    int* srcs_slot    = (int*)(sq + (size_t)e * HF);
    unsigned* offs    = (unsigned*)(srcs_slot + (size_t)e);
    unsigned* cursor  = offs + (size_t)(n + 1);
    unsigned* counts  = cursor + (size_t)n;
    unsigned* bsum    = counts + (size_t)n;

    float* x = (float*)d_out;            // [n, H]
    float* y = x + (size_t)n * HF;       // [e, H]

    int nb = (n + 511) / 512;

    hipMemsetAsync(counts, 0, (size_t)n * sizeof(unsigned), stream);

    k_prep<<<HF + 1, HF, 0, stream>>>(W_eg, W_sg, W_dg, W_du, W_su,
                                      time_feats, W_tp, b_tp,
                                      b_sg, b_dg, b_du, b_su,
                                      WegT, WT4, bias4);

    k_hist<<<(e + 255) / 256, 256, 0, stream>>>(dst, counts, e);
    k_scanA<<<nb, 256, 0, stream>>>(counts, bsum, n);
    k_scanC<<<nb, 512, 0, stream>>>(counts, bsum, offs, cursor, n);

    k_node_mfma<<<(n + 63) / 64, 256, 0, stream>>>(node_feats, WT4, bias4,
                                                   esrc16, edstA16, bh16, x, n);

    k_edge_mfma<<<(e + 63) / 64, 256, 0, stream>>>(edge_feats, src, dst,
                                                   cursor, srcs_slot,
                                                   WegT, b_eg,
                                                   esrc16, edstA16,
                                                   g_ln_e, b_ln_e,
                                                   sq, y, e);

    dim3 b2(HF, 4);
    k_node_fin<<<(n + 3) / 4, b2, 0, stream>>>(node_feats, offs, srcs_slot,
                                               sq, bh16,
                                               g_ln_n, b_ln_n, x, n);
}